// Round 11
// baseline (243.425 us; speedup 1.0000x reference)
//
#include <hip/hip_runtime.h>
#include <math.h>

#define TOKENS 16384
#define HIDDEN 2048
#define BM 256
#define BN 256
#define BK 64
#define NT (HIDDEN / BK)   // 32 K-tiles

typedef __attribute__((ext_vector_type(4))) float f32x4;
typedef __attribute__((ext_vector_type(8))) short s16x8;

__device__ __forceinline__ unsigned short f2bf(float f) {
  unsigned int u = __float_as_uint(f);
  u += 0x7fffu + ((u >> 16) & 1u);   // round-to-nearest-even
  return (unsigned short)(u >> 16);
}

// tanh-approx GELU via raw v_exp_f32 + v_rcp_f32; |err vs erf-gelu| ~1e-3.
__device__ __forceinline__ float fast_gelu(float y) {
  float t = y * fmaf(y * y, 0.044715f, 1.0f);
  float e = __builtin_amdgcn_exp2f(-2.3022082f * t);
  return y * __builtin_amdgcn_rcpf(1.0f + e);
}

// ---------------- kernel 0: W fp32 -> bf16 ----------------
__global__ __launch_bounds__(256) void wconv_kernel(const float* __restrict__ W,
                                                    unsigned short* __restrict__ Wb) {
  const int n4 = (HIDDEN * HIDDEN) / 4;
  for (int i = blockIdx.x * 256 + threadIdx.x; i < n4; i += gridDim.x * 256) {
    float4 v = *(const float4*)(W + (size_t)i * 4);
    ushort4 o;
    o.x = f2bf(v.x); o.y = f2bf(v.y); o.z = f2bf(v.z); o.w = f2bf(v.w);
    *(ushort4*)(Wb + (size_t)i * 4) = o;
  }
}

// ---------------- kernel 1: FUSED LayerNorm pre-pass + 256x256 4-phase bf16 GEMM ------
// Round-3 verified GEMM (141 us; 4-phase snake, BK=64, LDS 128 KiB, counted vmcnt(4),
// XOR swizzle both-sides, XCD swizzle, setprio) with LN fused as a per-block pre-pass:
// each block normalizes ITS OWN 256 A-rows (fp32 x -> bf16 xn in workspace), drains its
// stores (vmcnt(0) + barrier), then stages from xn. Correctness is self-contained —
// a block reads only rows it wrote itself (same-CU L1 is write-through; barrier orders
// waves). The 8 tn-sibling blocks write identical bytes redundantly (benign; same XCD
// via the swizzle, so x is HBM-fetched once per slab). LN's 30 us serial kernel
// collapses into traffic hidden under the GEMM's idle HBM headroom.

#define GLOAD(gp, lp) __builtin_amdgcn_global_load_lds( \
    (const __attribute__((address_space(1))) unsigned int*)(gp), \
    (__attribute__((address_space(3))) unsigned int*)(lp), 16, 0, 0)

__global__ __launch_bounds__(512, 1) void gemm_kernel(const float* __restrict__ x,
                                                      const float* __restrict__ gamma,
                                                      const float* __restrict__ beta,
                                                      const unsigned short* __restrict__ B,
                                                      const float* __restrict__ bias,
                                                      unsigned short* __restrict__ xn,
                                                      float* __restrict__ out) {
  __shared__ __attribute__((aligned(16))) char lds[131072];

  const int tid = threadIdx.x;
  const int lane = tid & 63;
  const int wave = tid >> 6;
  const int fr = lane & 15, hi = lane >> 4;

  // XCD-aware swizzle: 512 WGs, 512 % 8 == 0 -> bijective; each XCD owns an M-slab.
  const int wg = blockIdx.x;
  const int swz = (wg & 7) * 64 + (wg >> 3);
  const int tm = swz >> 3, tn = swz & 7;   // 64 M-tiles x 8 N-tiles
  const int row0 = tm * BM, col0 = tn * BN;

  const int wmi = wave >> 2;        // wave M index (0..1)
  const int wni = wave & 3;         // wave N index (0..3)
  const int hB = wni >> 1, gB = wni & 1;

  // ================= LN pre-pass: this block's 256 A-rows -> xn =================
  {
    const float rh = 1.0f / HIDDEN;
    for (int rr = 0; rr < 32; ++rr) {
      const int r = row0 + (wave << 5) + rr;
      const float* xr = x + (size_t)r * HIDDEN;
      float xv[32];
      float s = 0.f, ss = 0.f;
#pragma unroll
      for (int k = 0; k < 4; ++k) {
        const float4 v0 = *(const float4*)(xr + lane * 8 + k * 512);
        const float4 v1 = *(const float4*)(xr + lane * 8 + k * 512 + 4);
        xv[k*8+0]=v0.x; xv[k*8+1]=v0.y; xv[k*8+2]=v0.z; xv[k*8+3]=v0.w;
        xv[k*8+4]=v1.x; xv[k*8+5]=v1.y; xv[k*8+6]=v1.z; xv[k*8+7]=v1.w;
      }
#pragma unroll
      for (int j = 0; j < 32; ++j) { s += xv[j]; ss = fmaf(xv[j], xv[j], ss); }
#pragma unroll
      for (int off = 32; off > 0; off >>= 1) {
        s += __shfl_xor(s, off, 64);
        ss += __shfl_xor(ss, off, 64);
      }
      const float mean = s * rh;
      const float rstd = rsqrtf(ss * rh - mean * mean + 1e-5f);
      unsigned short* xw = xn + (size_t)r * HIDDEN;
#pragma unroll
      for (int k = 0; k < 4; ++k) {
        const float4 g0 = *(const float4*)(gamma + lane * 8 + k * 512);
        const float4 g1 = *(const float4*)(gamma + lane * 8 + k * 512 + 4);
        const float4 e0 = *(const float4*)(beta + lane * 8 + k * 512);
        const float4 e1 = *(const float4*)(beta + lane * 8 + k * 512 + 4);
        union { unsigned short h[8]; uint4 q; } pk;
        pk.h[0] = f2bf((xv[k*8+0]-mean)*rstd*g0.x + e0.x);
        pk.h[1] = f2bf((xv[k*8+1]-mean)*rstd*g0.y + e0.y);
        pk.h[2] = f2bf((xv[k*8+2]-mean)*rstd*g0.z + e0.z);
        pk.h[3] = f2bf((xv[k*8+3]-mean)*rstd*g0.w + e0.w);
        pk.h[4] = f2bf((xv[k*8+4]-mean)*rstd*g1.x + e1.x);
        pk.h[5] = f2bf((xv[k*8+5]-mean)*rstd*g1.y + e1.y);
        pk.h[6] = f2bf((xv[k*8+6]-mean)*rstd*g1.z + e1.z);
        pk.h[7] = f2bf((xv[k*8+7]-mean)*rstd*g1.w + e1.w);
        *(uint4*)(xw + lane * 8 + k * 512) = pk.q;
      }
    }
    asm volatile("s_waitcnt vmcnt(0)" ::: "memory");   // own stores drained to L2
    __builtin_amdgcn_s_barrier();                      // all waves' rows written
  }

  // ================= round-3 GEMM =================
  // staging geometry (per-lane gather, pre-swizzled source)
  const int rho = tid >> 3, sig = tid & 7;
  const int colgrp = ((sig ^ (rho & 7)) << 3);                 // k-element offset
  const unsigned short* Ap = xn + (size_t)(row0 + rho) * HIDDEN + colgrp;
  const unsigned short* Bp = B + (size_t)(col0 + ((rho >> 5) << 6) + (rho & 31)) * HIDDEN + colgrp;
  const int ldsWaveOff = wave << 10;                            // 64 lanes * 16B

  // ds_read per-lane constants (swizzled slot bytes for kk=0,1)
  const int s0 = ((hi ^ (fr & 7)) << 4);
  const int s1 = (((4 + hi) ^ (fr & 7)) << 4);
  const int aRowB = fr << 7;                        // fr*128
  const int bRowB = (((gB << 5) + fr) << 7);        // (gB*32+fr)*128

  auto stageA = [&](int tt, int bufd, int qm) {     // 2 calls: both halves of quarter qm
    const int tc = tt < NT ? tt : NT - 1;
    const unsigned short* g = Ap + (size_t)(qm << 6) * HIDDEN + tc * BK;
    GLOAD(g, lds + ((((bufd << 2) | qm) << 13)) + ldsWaveOff);
    GLOAD(g + (size_t)128 * HIDDEN, lds + ((((bufd << 2) | 2 | qm) << 13)) + ldsWaveOff);
  };
  auto stageB = [&](int tt, int bufd, int qn) {
    const int tc = tt < NT ? tt : NT - 1;
    const unsigned short* g = Bp + (size_t)(qn << 5) * HIDDEN + tc * BK;
    GLOAD(g, lds + 65536 + ((((bufd << 2) | qn) << 13)) + ldsWaveOff);
    GLOAD(g + (size_t)128 * HIDDEN, lds + 65536 + ((((bufd << 2) | 2 | qn) << 13)) + ldsWaveOff);
  };

  f32x4 acc[2][4][4] = {};
  s16x8 a[4][2], b[2][2];

  // prologue: tile0 fully + tile1's first 2 quarters, steady-state age order
  stageA(0, 0, 0); stageB(0, 0, 1); stageA(0, 0, 1); stageB(0, 0, 0);
  stageA(1, 1, 0); stageB(1, 1, 1);
  asm volatile("s_waitcnt vmcnt(4)" ::: "memory");   // tile0's 8 calls landed
  __builtin_amdgcn_s_barrier();

  for (int t = 0; t < NT; ++t) {
    const int buf = t & 1;
    const char* Abase = lds + (((buf << 2) | (wmi << 1)) << 13);
    const char* Bbase = lds + 65536 + (((buf << 2) | (hB << 1)) << 13);

    // ===== p0: quadrant (qm=0, qn=0) =====
#pragma unroll
    for (int mi = 0; mi < 4; ++mi) {
      a[mi][0] = *(const s16x8*)(Abase + mi * 2048 + aRowB + s0);
      a[mi][1] = *(const s16x8*)(Abase + mi * 2048 + aRowB + s1);
    }
#pragma unroll
    for (int nj = 0; nj < 2; ++nj) {
      b[nj][0] = *(const s16x8*)(Bbase + nj * 2048 + bRowB + s0);
      b[nj][1] = *(const s16x8*)(Bbase + nj * 2048 + bRowB + s1);
    }
    stageA(t + 1, buf ^ 1, 1);
    asm volatile("s_waitcnt lgkmcnt(8)" ::: "memory");
    __builtin_amdgcn_s_barrier();
    asm volatile("s_waitcnt lgkmcnt(0)" ::: "memory");
    __builtin_amdgcn_s_setprio(1);
#pragma unroll
    for (int mi = 0; mi < 4; ++mi)
#pragma unroll
      for (int nj = 0; nj < 2; ++nj)
#pragma unroll
        for (int kk = 0; kk < 2; ++kk)
          acc[0][mi][nj] = __builtin_amdgcn_mfma_f32_16x16x32_bf16(a[mi][kk], b[nj][kk], acc[0][mi][nj], 0, 0, 0);
    __builtin_amdgcn_s_setprio(0);
    __builtin_amdgcn_s_barrier();

    // ===== p1: quadrant (qm=0, qn=1) — reuse a =====
#pragma unroll
    for (int nj = 0; nj < 2; ++nj) {
      b[nj][0] = *(const s16x8*)(Bbase + 8192 + nj * 2048 + bRowB + s0);
      b[nj][1] = *(const s16x8*)(Bbase + 8192 + nj * 2048 + bRowB + s1);
    }
    stageB(t + 1, buf ^ 1, 0);
    __builtin_amdgcn_s_barrier();
    asm volatile("s_waitcnt lgkmcnt(0)" ::: "memory");
    __builtin_amdgcn_s_setprio(1);
#pragma unroll
    for (int mi = 0; mi < 4; ++mi)
#pragma unroll
      for (int nj = 0; nj < 2; ++nj)
#pragma unroll
        for (int kk = 0; kk < 2; ++kk)
          acc[0][mi][2 + nj] = __builtin_amdgcn_mfma_f32_16x16x32_bf16(a[mi][kk], b[nj][kk], acc[0][mi][2 + nj], 0, 0, 0);
    __builtin_amdgcn_s_setprio(0);
    __builtin_amdgcn_s_barrier();

    // ===== p2: quadrant (qm=1, qn=1) — reuse b =====
#pragma unroll
    for (int mi = 0; mi < 4; ++mi) {
      a[mi][0] = *(const s16x8*)(Abase + 8192 + mi * 2048 + aRowB + s0);
      a[mi][1] = *(const s16x8*)(Abase + 8192 + mi * 2048 + aRowB + s1);
    }
    stageA(t + 2, buf, 0);
    asm volatile("s_waitcnt lgkmcnt(4)" ::: "memory");
    __builtin_amdgcn_s_barrier();
    asm volatile("s_waitcnt lgkmcnt(0)" ::: "memory");
    __builtin_amdgcn_s_setprio(1);
#pragma unroll
    for (int mi = 0; mi < 4; ++mi)
#pragma unroll
      for (int nj = 0; nj < 2; ++nj)
#pragma unroll
        for (int kk = 0; kk < 2; ++kk)
          acc[1][mi][2 + nj] = __builtin_amdgcn_mfma_f32_16x16x32_bf16(a[mi][kk], b[nj][kk], acc[1][mi][2 + nj], 0, 0, 0);
    __builtin_amdgcn_s_setprio(0);
    __builtin_amdgcn_s_barrier();

    // ===== p3: quadrant (qm=1, qn=0) — reuse a; K-tile boundary vmcnt =====
#pragma unroll
    for (int nj = 0; nj < 2; ++nj) {
      b[nj][0] = *(const s16x8*)(Bbase + nj * 2048 + bRowB + s0);
      b[nj][1] = *(const s16x8*)(Bbase + nj * 2048 + bRowB + s1);
    }
    stageB(t + 2, buf, 1);
    asm volatile("s_waitcnt vmcnt(4)" ::: "memory");   // counted: next tile landed, 4 in flight
    __builtin_amdgcn_s_barrier();
    asm volatile("s_waitcnt lgkmcnt(0)" ::: "memory");
    __builtin_amdgcn_s_setprio(1);
#pragma unroll
    for (int mi = 0; mi < 4; ++mi)
#pragma unroll
      for (int nj = 0; nj < 2; ++nj)
#pragma unroll
        for (int kk = 0; kk < 2; ++kk)
          acc[1][mi][nj] = __builtin_amdgcn_mfma_f32_16x16x32_bf16(a[mi][kk], b[nj][kk], acc[1][mi][nj], 0, 0, 0);
    __builtin_amdgcn_s_setprio(0);
    __builtin_amdgcn_s_barrier();
  }

  asm volatile("s_waitcnt vmcnt(0)" ::: "memory");   // drain clamped tail prefetches

  // ---- epilogue: bias + fast GELU, fp32 store ----
  float bcol[4];
#pragma unroll
  for (int ni = 0; ni < 4; ++ni)
    bcol[ni] = bias[col0 + (wni << 6) + ni * 16 + fr];

#pragma unroll
  for (int qm = 0; qm < 2; ++qm)
#pragma unroll
    for (int mi = 0; mi < 4; ++mi)
#pragma unroll
      for (int ni = 0; ni < 4; ++ni) {
        const int c = col0 + (wni << 6) + ni * 16 + fr;
#pragma unroll
        for (int j = 0; j < 4; ++j) {
          const int r = row0 + wmi * 128 + qm * 64 + mi * 16 + hi * 4 + j;
          float y = acc[qm][mi][ni][j] + bcol[ni];
          out[(size_t)r * HIDDEN + c] = fast_gelu(y);
        }
      }
}

extern "C" void kernel_launch(void* const* d_in, const int* in_sizes, int n_in,
                              void* d_out, int out_size, void* d_ws, size_t ws_size,
                              hipStream_t stream) {
  const float* x     = (const float*)d_in[0];
  const float* gamma = (const float*)d_in[1];
  const float* beta  = (const float*)d_in[2];
  const float* W     = (const float*)d_in[3];
  const float* bias  = (const float*)d_in[4];
  float* out = (float*)d_out;

  unsigned short* xn = (unsigned short*)d_ws;
  unsigned short* wb = (unsigned short*)((char*)d_ws + (size_t)TOKENS * HIDDEN * 2);

  hipLaunchKernelGGL(wconv_kernel, dim3(1024), dim3(256), 0, stream, W, wb);
  hipLaunchKernelGGL(gemm_kernel, dim3((TOKENS / BM) * (HIDDEN / BN)), dim3(512), 0, stream,
                     x, gamma, beta, wb, bias, xn, out);
}